// Round 10
// baseline (125.455 us; speedup 1.0000x reference)
//
#include <hip/hip_runtime.h>
#include <hip/hip_bf16.h>
#include <math.h>

// HIR rainfall-runoff scan — tolerance-bracketed time-chunking + exact fixup.
//
// V11 = V10 (117.4 us best; pass1 43.5) + wave-paired bracket warm-up.
//  * Machine model (V5/V9/V10, quantified): per-wave step cost 250 cy at
//    1 wave/SIMD; 144 cy/wave-step at 2 waves/SIMD (V5, VALUBusy 68%).
//    V5 lost because it DUPLICATED work; here the two bracket chains are
//    SPLIT across two waves of one 128-thread block:
//      wave 0: hi chain + gw (continues into the main chunk)
//      wave 1: lo chain (sms only), writes slo to LDS, then idles at barriers
//    Same total step count as V10; warm-up runs at ~150 cy/step.
//    Exact chunks (c*64 <= W): wave 1 skips warm-up entirely.
//  * Numerics bit-identical to V10: stepw's s-update never reads gw (V5-
//    validated), so wave1's stepw lo-chain == dstep's lo section; wave0's
//    stepw == dstep's hi section.
//  * Store-transpose phase split across both waves (32 columns each).
//  * Fixup unchanged (thread-per-(b,c), early-exit merged, PIPE3).
//
// Q[b,t] (t>=1) = fluxes from carry entering step t; Q[b,0] uses the FINAL
// carry (jnp.roll wraparound) with t=0 inputs (chunk NC-1 owner writes it).

struct P {
    float INSC, SMSC, RecK, g1, lc, k1, k2, k3, c2;
    // g1=1-RecK, lc=log2(COEFF), k1=SUB/SMSC, k2=CRAK/SMSC, k3=10/SMSC,
    // c2=-SQ/SMSC*log2(e)
};

__device__ __forceinline__ P make_params(const float* pINSC, const float* pCOEFF,
                                         const float* pSQ,   const float* pSMSC,
                                         const float* pSUB,  const float* pCRAK,
                                         const float* pRecK) {
    P p;
    p.INSC      = fminf(fmaxf(pINSC[0]  * 5.0f,   0.5f),   5.0f);
    float COEFF = fminf(fmaxf(pCOEFF[0] * 400.0f, 50.0f),  400.0f);
    float SQ    = fminf(fmaxf(pSQ[0]    * 6.0f,   0.0f),   6.0f);
    p.SMSC      = fminf(fmaxf(pSMSC[0]  * 500.0f, 50.0f),  500.0f);
    float SUB   = fminf(fmaxf(pSUB[0],  0.0f), 1.0f);
    float CRAK  = fminf(fmaxf(pCRAK[0], 0.0f), 1.0f);
    p.RecK      = fminf(fmaxf(pRecK[0]  * 0.3f,   0.003f), 0.3f);
    p.g1 = 1.0f - p.RecK;
    p.lc = log2f(COEFF);
    float inv = 1.0f / p.SMSC;
    p.k1 = SUB * inv;
    p.k2 = CRAK * inv;
    p.k3 = 10.0f * inv;
    p.c2 = (-SQ * inv) * 1.44269504088896340736f;
    return p;
}

// Full step with Q. Critical sms chain: fminf -> fmaf -> exp2f -> fminf ->
// mul -> fmaf. Everything else is off-path.
__device__ __forceinline__ float step(float Prec, float PET, float& sms, float& gw, const P& p) {
    float INT  = fminf(fminf(p.INSC, PET), Prec);
    float INR  = Prec - INT;
    float POT  = PET - INT;
    float S    = fminf(sms, p.SMSC);                 // lower clamp provably slack
    float u    = fmaf(-p.k1, S, 1.0f);
    float v    = fmaf(-p.k2, S, 1.0f);
    float ETS  = fminf(POT, p.k3 * S);
    float SmE  = S - ETS;
    float e    = exp2f(fmaf(p.c2, S, p.lc));         // cap = COEFF*2^(c2*S)
    float RMO  = fminf(INR, e);
    float w    = u * RMO;                            // t2 = RMO - SRUN
    float s2   = fmaf(v, w, SmE);                    // S + SMF - ETS
    float SMF  = v * w;
    float REC  = w - SMF;
    float RECnew = REC + fmaxf(s2 - p.SMSC, 0.0f);
    float BAS  = p.RecK * gw;
    float Q    = (INR - w) + BAS;                    // IRUN + SRUN + BAS
    gw  = fmaf(p.g1, gw, RECnew);
    sms = s2;
    return Q;
}

// Warm-up / state-advance step without Q (single chain, carries gw).
// The s-update never reads gw, so a lane running a bracket sms-chain can use
// this unchanged (its gw output is discarded) — V5-validated.
__device__ __forceinline__ void stepw(float Prec, float PET, float& sms, float& gw, const P& p) {
    float INT  = fminf(fminf(p.INSC, PET), Prec);
    float INR  = Prec - INT;
    float POT  = PET - INT;
    float S    = fminf(sms, p.SMSC);
    float u    = fmaf(-p.k1, S, 1.0f);
    float v    = fmaf(-p.k2, S, 1.0f);
    float ETS  = fminf(POT, p.k3 * S);
    float SmE  = S - ETS;
    float e    = exp2f(fmaf(p.c2, S, p.lc));
    float RMO  = fminf(INR, e);
    float w    = u * RMO;
    float s2   = fmaf(v, w, SmE);
    float SMF  = v * w;
    float REC  = w - SMF;
    float RECnew = REC + fmaxf(s2 - p.SMSC, 0.0f);
    gw  = fmaf(p.g1, gw, RECnew);
    sms = s2;
}

// Dual-bracket warm-up step (fallback path only).
__device__ __forceinline__ void dstep(float Prec, float PET,
                                      float& slo, float& shi, float& gw, const P& p) {
    float INT = fminf(fminf(p.INSC, PET), Prec);
    float INR = Prec - INT;
    float POT = PET - INT;
    {   // hi + gw
        float S    = fminf(shi, p.SMSC);
        float u    = fmaf(-p.k1, S, 1.0f);
        float v    = fmaf(-p.k2, S, 1.0f);
        float ETS  = fminf(POT, p.k3 * S);
        float SmE  = S - ETS;
        float e    = exp2f(fmaf(p.c2, S, p.lc));
        float RMO  = fminf(INR, e);
        float w    = u * RMO;
        float s2   = fmaf(v, w, SmE);
        float SMF  = v * w;
        float REC  = w - SMF;
        float RECnew = REC + fmaxf(s2 - p.SMSC, 0.0f);
        gw  = fmaf(p.g1, gw, RECnew);
        shi = s2;
    }
    {   // lo, sms only
        float S    = fminf(slo, p.SMSC);
        float u    = fmaf(-p.k1, S, 1.0f);
        float v    = fmaf(-p.k2, S, 1.0f);
        float ETS  = fminf(POT, p.k3 * S);
        float SmE  = S - ETS;
        float e    = exp2f(fmaf(p.c2, S, p.lc));
        float RMO  = fminf(INR, e);
        float w    = u * RMO;
        slo = fmaf(v, w, SmE);
    }
}

#define MERGE_TOL 0.75f

// ---------------------------------------------------------------------------
// 3-buffer, 4-float4-batch software pipeline (distance-2, no register copies).
// Ambient names: bp (const float4* batch base), B0/B1/B2 (float4[4]).
// Batch j lives in B[j%3]; the load for batch j+2 issues in batch j's slot.
// Clamped tail loads always target already-consumed buffers.
// ---------------------------------------------------------------------------

#define LB(DST, K, NB) do { int _kn = (K) < (NB) ? (K) : (NB) - 1;              \
    _Pragma("unroll") for (int _q = 0; _q < 4; ++_q) DST[_q] = bp[4 * _kn + _q]; } while (0)

#define PIPE3(NB, CB) do { if ((NB) > 0) {                                      \
    LB(B0, 0, (NB)); LB(B1, 1, (NB));                                           \
    int _j = 0;                                                                 \
    for (; _j + 3 <= (NB); _j += 3) {                                           \
        LB(B2, _j + 2, (NB)); CB(B0, _j);                                       \
        LB(B0, _j + 3, (NB)); CB(B1, _j + 1);                                   \
        LB(B1, _j + 4, (NB)); CB(B2, _j + 2);                                   \
    }                                                                           \
    if (_j < (NB)) { LB(B2, _j + 2, (NB)); CB(B0, _j); ++_j;                    \
        if (_j < (NB)) { LB(B0, _j + 2, (NB)); CB(B1, _j); } }                  \
} } while (0)

// Compute-batch macros (8 steps per batch).
#define CBW(BUF, J) do { _Pragma("unroll") for (int _m = 0; _m < 4; ++_m) {     \
    stepw(BUF[_m].x, BUF[_m].y, shi, gw, p);                                    \
    stepw(BUF[_m].z, BUF[_m].w, shi, gw, p); } } while (0)

#define CBD(BUF, J) do { _Pragma("unroll") for (int _m = 0; _m < 4; ++_m) {     \
    dstep(BUF[_m].x, BUF[_m].y, slo, shi, gw, p);                               \
    dstep(BUF[_m].z, BUF[_m].w, slo, shi, gw, p); } } while (0)

#define CBM(BUF, J) do { int _tb = 8 * (J);                                     \
    _Pragma("unroll") for (int _m = 0; _m < 4; ++_m) {                          \
    float _qa = step(BUF[_m].x, BUF[_m].y, sms, gw, p);                         \
    float _qb = step(BUF[_m].z, BUF[_m].w, sms, gw, p);                         \
    lds_q[_tb + 2 * _m][l] = _qa; lds_q[_tb + 2 * _m + 1][l] = _qb; } } while (0)

#define CBF(BUF, J) do { _Pragma("unroll") for (int _m = 0; _m < 4; ++_m) {     \
    float _qa = step(BUF[_m].x, BUF[_m].y, sms, gw, p);                         \
    float _qb = step(BUF[_m].z, BUF[_m].w, sms, gw, p);                         \
    orow2[ib0 + 4 * (J) + _m] = make_float2(_qa, _qb); } } while (0)

// ---------------------------------------------------------------------------
// Pass 1 (wave-paired): 128-thread block = 2 waves sharing (row-group, c).
// Wave 0: hi chain + gw, then main chunk. Wave 1: lo chain, writes slo to
// LDS, then only barriers + half the store-transpose.
// ---------------------------------------------------------------------------

template<int T, int NC, int W>
__global__ __launch_bounds__(128, 1)
void hir_pass1(const float* __restrict__ inputs,
               const float* __restrict__ pINSC,  const float* __restrict__ pCOEFF,
               const float* __restrict__ pSQ,    const float* __restrict__ pSMSC,
               const float* __restrict__ pSUB,   const float* __restrict__ pCRAK,
               const float* __restrict__ pRecK,
               float* __restrict__ out, float4* __restrict__ st, int B)
{
    __shared__ float lds_q[64][65];        // [t_local][lane], +1 pad: bank-free
    __shared__ float lds_slo[64];
    const int tid = threadIdx.x;
    const int l = tid & 63;
    const int w = tid >> 6;                // 0 = hi(+gw,+main), 1 = lo
    const int nbg = B >> 6;                // row groups of 64
    const int g = blockIdx.x % nbg;
    const int c = blockIdx.x / nbg;        // block-uniform
    const int b = (g << 6) + l;

    P p = make_params(pINSC, pCOEFF, pSQ, pSMSC, pSUB, pCRAK, pRecK);

    const float4* __restrict__ rp = (const float4*)(inputs + (size_t)b * (2 * T));
    float* __restrict__ orow = out + (size_t)b * T;

    constexpr int CH = T / NC;             // 64 steps
    const int i1 = (c * CH) >> 1;          // first main float4 index
    int i0 = i1 - (W >> 1);                // warm-up start (W/2 float4s)
    const bool exact = (i0 <= 0);
    if (i0 < 0) i0 = 0;

    // Wave 0 carries the hi chain (or the true chain when exact) + gw.
    // Wave 1 carries the lo chain (starts at 0; gw discarded).
    float s  = exact ? 0.0f : (w ? 0.0f : p.SMSC);
    float gw = 0.0f;
    float4 B0[4], B1[4], B2[4];

    // ---- Warm-up: each wave runs ONE chain (wave-uniform control flow).
    //      Exact chunks: wave 1's chain would duplicate wave 0's -> skip. ----
    if (w == 0 || !exact) {
        const int nb = (i1 - i0) >> 2;     // in {0, 8, 16, 24, 32, 40}
        const float4* bp = rp + i0;
        float& shi = s;                    // CBW advances "shi"
        PIPE3(nb, CBW);
    }

    // ---- Exchange: wave 1 publishes slo ----
    if (w) lds_slo[l] = s;
    __syncthreads();

    float q0 = 0.0f;
    const bool hasq0 = (c == NC - 1);
    if (w == 0) {
        const float slo = exact ? s : lds_slo[l];
        const float shi = s;
        const bool merged = exact || ((shi - slo) <= MERGE_TOL);
        float sms = exact ? s : (0.5f * (slo + shi));

        // ---- Main chunk: 8 batches, Q -> LDS (bank-conflict-free) ----
        {
            const float4* bp = rp + i1;
            PIPE3(8, CBM);
        }

        st[(size_t)c * B + b] = make_float4(sms, gw, merged ? 1.0f : 0.0f, 0.0f);

        if (hasq0) {                       // Q[b,0] from final carry (roll)
            float4 f0 = rp[0];
            float ss = sms, gg = gw;
            q0 = step(f0.x, f0.y, ss, gg, p);
        }
    }

    __syncthreads();                       // lds_q visible to both waves

    // ---- Store phase: split columns across the two waves (32 each).
    //      out[b0+j][t1+l] = lds_q[l][j]; banks (l+j)%32 conflict-free. ----
    const int b0 = g << 6;
    const int t1 = c * CH;
    const int j0 = w << 5;
    if (c == 0) {
        if (l > 0) {                       // lane 0 would write t=0 (owned by roll)
            for (int j = j0; j < j0 + 32; ++j)
                out[(size_t)(b0 + j) * T + l] = lds_q[l][j];
        }
    } else {
        for (int j = j0; j < j0 + 32; ++j)
            out[(size_t)(b0 + j) * T + t1 + l] = lds_q[l][j];
    }
    if (w == 0 && hasq0) orow[0] = q0;
}

// ---------------------------------------------------------------------------
// Fixup: thread per (b, c). Merged -> one coalesced st read, exit. Unmerged
// -> walk back to nearest merged predecessor m (chunk 0 is always exact =>
// merged), advance store-free through m+1..c-1, recompute chunk c exactly
// with direct out stores. Pipelined loads throughout. Same semantics as the
// sequential per-row fixup: merged states are accepted as-is.
// ---------------------------------------------------------------------------

template<int T, int NC>
__global__ __launch_bounds__(64)
void hir_fixup(const float* __restrict__ inputs,
               const float* __restrict__ pINSC,  const float* __restrict__ pCOEFF,
               const float* __restrict__ pSQ,    const float* __restrict__ pSMSC,
               const float* __restrict__ pSUB,   const float* __restrict__ pCRAK,
               const float* __restrict__ pRecK,
               float* __restrict__ out, const float4* __restrict__ st, int B)
{
    const int gid = blockIdx.x * 64 + threadIdx.x;
    const int b = gid % B;
    const int c = gid / B;
    if (c >= NC) return;

    float4 sc = st[(size_t)c * B + b];
    if (sc.z != 0.0f) return;              // merged -> nothing to fix

    P p = make_params(pINSC, pCOEFF, pSQ, pSMSC, pSUB, pCRAK, pRecK);
    constexpr int CH = T / NC;

    const float4* __restrict__ rp = (const float4*)(inputs + (size_t)b * (2 * T));
    float* __restrict__ orow = out + (size_t)b * T;
    float2* __restrict__ orow2 = (float2*)orow;

    // Walk back to nearest merged predecessor (c >= 1 here: chunk 0 merged).
    int m = c - 1;
    float4 sm = st[(size_t)m * B + b];
    while (sm.z == 0.0f) { --m; sm = st[(size_t)m * B + b]; }
    float sms = sm.x, gw = sm.y;

    float4 B0[4], B1[4], B2[4];

    // Advance state through chunks m+1..c-1 (no stores), pipelined.
    {
        const int ia = ((m + 1) * CH) >> 1;
        const int ibx = (c * CH) >> 1;
        const int nb = (ibx - ia) >> 2;    // multiple of 8 (or 0)
        const float4* bp = rp + ia;
        float& shi = sms;                  // CBW advances "shi"
        PIPE3(nb, CBW);
    }

    // Recompute chunk c exactly, with stores, pipelined.
    {
        const int ib0 = (c * CH) >> 1;     // float2 output base index
        const float4* bp = rp + ib0;
        PIPE3(8, CBF);
    }

    if (c == NC - 1) {                     // rewrite the t=0 wraparound output
        float4 f0 = rp[0];
        float ss = sms, gg = gw;
        orow[0] = step(f0.x, f0.y, ss, gg, p);
    }
}

// Fallback: monolithic sequential (odd shapes / tiny workspace).
template<int T>
__global__ __launch_bounds__(64, 1)
void hir_scan_kernel(const float* __restrict__ inputs,
                     const float* __restrict__ pINSC,  const float* __restrict__ pCOEFF,
                     const float* __restrict__ pSQ,    const float* __restrict__ pSMSC,
                     const float* __restrict__ pSUB,   const float* __restrict__ pCRAK,
                     const float* __restrict__ pRecK,
                     float* __restrict__ out, int B)
{
    int b = blockIdx.x * blockDim.x + threadIdx.x;
    if (b >= B) return;
    P p = make_params(pINSC, pCOEFF, pSQ, pSMSC, pSUB, pCRAK, pRecK);
    const float4* __restrict__ rp = (const float4*)(inputs + (size_t)b * (2 * T));
    float* __restrict__ orow = out + (size_t)b * T;
    float sms = 0.0f, gw = 0.0f;
    float4 cur = rp[0];
    const float P0 = cur.x, E0 = cur.y;
    constexpr int NI = T / 2;
    for (int i = 0; i < NI; ++i) {
        int ni = (i + 1 < NI) ? (i + 1) : i;
        float4 nxt = rp[ni];
        float qa = step(cur.x, cur.y, sms, gw, p);
        float qb = step(cur.z, cur.w, sms, gw, p);
        if (i == 0) { orow[1] = qb; }
        else        { ((float2*)orow)[i] = make_float2(qa, qb); }
        cur = nxt;
    }
    float ss = sms, gg = gw;
    orow[0] = step(P0, E0, ss, gg, p);
}

extern "C" void kernel_launch(void* const* d_in, const int* in_sizes, int n_in,
                              void* d_out, int out_size, void* d_ws, size_t ws_size,
                              hipStream_t stream) {
    (void)n_in; (void)out_size;
    constexpr int T  = 1024;
    constexpr int NC = 16;    // chunks (CH=64)
    constexpr int W  = 320;   // warm-up: gap ~250*e^(-.0201*320) ~ 0.4 < 0.75
    const float* inputs = (const float*)d_in[0];
    const float* INSC   = (const float*)d_in[1];
    const float* COEFF  = (const float*)d_in[2];
    const float* SQ     = (const float*)d_in[3];
    const float* SMSC   = (const float*)d_in[4];
    const float* SUB    = (const float*)d_in[5];
    const float* CRAK   = (const float*)d_in[6];
    const float* RecK   = (const float*)d_in[7];
    float* out = (float*)d_out;

    int B = in_sizes[0] / (2 * T);            // 4096 for the reference shape
    size_t stBytes = (size_t)B * NC * sizeof(float4);   // 1 MB

    if ((B % 64) == 0 && ws_size >= stBytes) {
        float4* st = (float4*)d_ws;
        int blocksP = (B >> 6) * NC;          // 1024 blocks x 2 waves = 2048 waves
        hir_pass1<T, NC, W><<<dim3(blocksP), dim3(128), 0, stream>>>(
            inputs, INSC, COEFF, SQ, SMSC, SUB, CRAK, RecK, out, st, B);
        long total = (long)B * NC;
        int blocksF = (int)((total + 63) / 64);
        hir_fixup<T, NC><<<dim3(blocksF), dim3(64), 0, stream>>>(
            inputs, INSC, COEFF, SQ, SMSC, SUB, CRAK, RecK, out, st, B);
        return;
    }

    int blocks = (B + 63) / 64;
    hir_scan_kernel<T><<<dim3(blocks), dim3(64), 0, stream>>>(
        inputs, INSC, COEFF, SQ, SMSC, SUB, CRAK, RecK, out, B);
}